// Round 14
// baseline (375.521 us; speedup 1.0000x reference)
//
#include <hip/hip_runtime.h>

typedef unsigned short u16;
typedef unsigned int u32;
typedef float f32x4 __attribute__((ext_vector_type(4)));
typedef short bfx8 __attribute__((ext_vector_type(8)));

#define D_DIM 512

__device__ __forceinline__ float bits2f(u32 b) {
    return __uint_as_float(b << 16);
}
__device__ __forceinline__ u16 f2b_bits(float f) {
    u32 u = __float_as_uint(f);
    u32 r = (u + 0x7fffu + ((u >> 16) & 1u)) >> 16;  // RNE
    return (u16)r;
}

// ---------------- prep: weight transpose + degree count (conv moved out) ----------
__global__ __launch_bounds__(256) void prepcnt_k(
    const float* __restrict__ Waa, const float* __restrict__ Wba,
    const float* __restrict__ Wab,
    u16* __restrict__ WtC, u16* __restrict__ WtAb,
    int nbPrep,
    const int* __restrict__ d0, int* __restrict__ c0, int E0,
    const int* __restrict__ d1, int* __restrict__ c1, int E1,
    const int* __restrict__ d2, int* __restrict__ c2, int E2) {
    int g = blockIdx.x, tid = threadIdx.x;
    if (g < nbPrep) {
        int idx = g * 256 + tid;
        if (idx < 512 * 1024) {
            int n = idx >> 10, k = idx & 1023;
            float v = (k < 512) ? Waa[k * 512 + n] : Wba[(k - 512) * 512 + n];
            WtC[idx] = f2b_bits(v);
        } else {
            int idx2 = idx - 512 * 1024;
            int n = idx2 >> 9, k = idx2 & 511;
            WtAb[idx2] = f2b_bits(Wab[k * 512 + n]);
        }
    } else {
        int i = (g - nbPrep) * 256 + tid;
        if (i < E0) atomicAdd(&c0[d0[i]], 1);
        else if (i < E0 + E1) atomicAdd(&c1[d1[i - E0]], 1);
        else if (i < E0 + E1 + E2) atomicAdd(&c2[d2[i - E0 - E1]], 1);
    }
}

// ---------------- parallel scan: chunk sums (CH=256) ----------------
__global__ __launch_bounds__(256) void chunksum_k(
    const int* __restrict__ cnt, int* __restrict__ csum,
    int n0, int n1, int n2, int nc0, int nc1, int nc2) {
    __shared__ int ws4[4];
    int g = blockIdx.x;
    int lc, base, n, cbase;
    if (g < nc0) { lc = g; base = 0; n = n0; cbase = 0; }
    else if (g < nc0 + nc1) { lc = g - nc0; base = n0; n = n1; cbase = nc0; }
    else { lc = g - nc0 - nc1; base = n0 + n1; n = n2; cbase = nc0 + nc1; }
    int tid = threadIdx.x, lane = tid & 63, wv = tid >> 6;
    int i = lc * 256 + tid;
    int v = (i < n) ? cnt[base + i] : 0;
#pragma unroll
    for (int d = 32; d; d >>= 1) v += __shfl_down(v, d, 64);
    if (lane == 0) ws4[wv] = v;
    __syncthreads();
    if (tid == 0) csum[cbase + lc] = ws4[0] + ws4[1] + ws4[2] + ws4[3];
}

// ---------------- parallel scan: exclusive scan of chunk sums (1 block) ----------------
__global__ __launch_bounds__(256) void chunkscan_k(int* __restrict__ csum,
                                                   int nc0, int nc1, int nc2) {
    __shared__ int ws4[4];
    int tid = threadIdx.x, lane = tid & 63, wv = tid >> 6;
    int ncs[3] = {nc0, nc1, nc2};
    int cb = 0;
    for (int e = 0; e < 3; e++) {
        int nc = ncs[e];  // requires nc <= 256 (N <= 65536)
        int v = (tid < nc) ? csum[cb + tid] : 0;
        int x = v;
#pragma unroll
        for (int d = 1; d < 64; d <<= 1) {
            int t = __shfl_up(x, d, 64);
            if (lane >= d) x += t;
        }
        if (lane == 63) ws4[wv] = x;
        __syncthreads();
        int woff = 0;
        for (int w = 0; w < wv; w++) woff += ws4[w];
        if (tid < nc) csum[cb + tid] = woff + x - v;  // exclusive
        __syncthreads();
        cb += nc;
    }
}

// ---------------- parallel scan: final per-element exclusive offsets ----------------
__global__ __launch_bounds__(256) void scanfinal_k(
    const int* __restrict__ cnt, const int* __restrict__ csum, int* __restrict__ cur,
    int n0, int n1, int n2, int nc0, int nc1, int nc2) {
    __shared__ int ws4[4];
    int g = blockIdx.x;
    int lc, base, n, cbase;
    if (g < nc0) { lc = g; base = 0; n = n0; cbase = 0; }
    else if (g < nc0 + nc1) { lc = g - nc0; base = n0; n = n1; cbase = nc0; }
    else { lc = g - nc0 - nc1; base = n0 + n1; n = n2; cbase = nc0 + nc1; }
    int tid = threadIdx.x, lane = tid & 63, wv = tid >> 6;
    int i = lc * 256 + tid;
    int v = (i < n) ? cnt[base + i] : 0;
    int x = v;
#pragma unroll
    for (int d = 1; d < 64; d <<= 1) {
        int t = __shfl_up(x, d, 64);
        if (lane >= d) x += t;
    }
    if (lane == 63) ws4[wv] = x;
    __syncthreads();
    int woff = 0;
    for (int w = 0; w < wv; w++) woff += ws4[w];
    if (i < n) cur[base + i] = csum[cbase + lc] + woff + x - v;
}

// ---------------- fused CSR fill + feature conversion ----------------
// fill and conv are mutually independent; both must precede pull. Running
// conv's grid-stride blocks in the same launch hides fill's ~20us of atomic
// work under conv's ~60us of streaming (they were serial before).
__global__ __launch_bounds__(256) void fillconv_k(
    const int* __restrict__ s0, const int* __restrict__ d0,
    int* __restrict__ u0, int* __restrict__ r0, int E0,
    const int* __restrict__ s1, const int* __restrict__ d1,
    int* __restrict__ u1, int* __restrict__ r1, int E1,
    const int* __restrict__ s2, const int* __restrict__ d2,
    int* __restrict__ u2, int* __restrict__ r2, int E2,
    int nbFill,
    const float* __restrict__ fa, const float* __restrict__ fb,
    u16* __restrict__ oa, u16* __restrict__ ob, int nA8, int nTot8, int nbConv) {
    int g = blockIdx.x, tid = threadIdx.x;
    if (g < nbFill) {
        int i = g * 256 + tid;
        if (i < E0) { int slot = atomicAdd(&u0[d0[i]], 1); r0[slot] = s0[i]; }
        else if (i < E0 + E1) { int j = i - E0; int slot = atomicAdd(&u1[d1[j]], 1); r1[slot] = s1[j]; }
        else if (i < E0 + E1 + E2) { int j = i - E0 - E1; int slot = atomicAdd(&u2[d2[j]], 1); r2[slot] = s2[j]; }
    } else if (nbConv > 0) {
        for (int i = (g - nbFill) * 256 + tid; i < nTot8; i += nbConv * 256) {
            const float* src; u16* dst; int j;
            if (i < nA8) { src = fa; dst = oa; j = i; }
            else { src = fb; dst = ob; j = i - nA8; }
            f32x4 a = *(const f32x4*)(src + (size_t)j * 8);
            f32x4 b = *(const f32x4*)(src + (size_t)j * 8 + 4);
            u16 o[8];
            o[0] = f2b_bits(a[0]); o[1] = f2b_bits(a[1]); o[2] = f2b_bits(a[2]); o[3] = f2b_bits(a[3]);
            o[4] = f2b_bits(b[0]); o[5] = f2b_bits(b[1]); o[6] = f2b_bits(b[2]); o[7] = f2b_bits(b[3]);
            *(bfx8*)(dst + (size_t)j * 8) = *(bfx8*)o;
        }
    }
}

// ---------------- fused pull-mean (wave per (etype,node)), 4-way MLP ----------------
__global__ __launch_bounds__(256) void pull3_k(
    const u16* __restrict__ fAb, const u16* __restrict__ fBb,
    const float* __restrict__ fAf, const float* __restrict__ fBf, int usebf,
    const int* __restrict__ curb, const int* __restrict__ cntb,
    const int* __restrict__ csr0, const int* __restrict__ csr1,
    const int* __restrict__ csr2,
    u16* __restrict__ Acat, u16* __restrict__ Aab, int NA, int NB) {
    int wid = threadIdx.x >> 6, lane = threadIdx.x & 63;
    int t = blockIdx.x * 4 + wid;
    if (t >= 2 * NA + NB) return;
    const u16* fb; const float* ff; const int* csr; u16* ap;
    if (t < NA) { fb = fAb; ff = fAf; csr = csr0; ap = Acat + (size_t)t * 1024; }
    else if (t < 2 * NA) { fb = fBb; ff = fBf; csr = csr1; ap = Acat + (size_t)(t - NA) * 1024 + 512; }
    else { fb = fAb; ff = fAf; csr = csr2; ap = Aab + (size_t)(t - 2 * NA) * 512; }
    int end = curb[t], c = cntb[t], beg = end - c;
    float acc[8] = {};
    if (usebf) {
        int j = beg;
        for (; j + 4 <= end; j += 4) {
            int s0 = csr[j], s1 = csr[j + 1], s2 = csr[j + 2], s3 = csr[j + 3];
            bfx8 v0 = *(const bfx8*)(fb + (size_t)s0 * D_DIM + lane * 8);
            bfx8 v1 = *(const bfx8*)(fb + (size_t)s1 * D_DIM + lane * 8);
            bfx8 v2 = *(const bfx8*)(fb + (size_t)s2 * D_DIM + lane * 8);
            bfx8 v3 = *(const bfx8*)(fb + (size_t)s3 * D_DIM + lane * 8);
#pragma unroll
            for (int i = 0; i < 8; i++) {
                acc[i] += (bits2f((u32)(u16)v0[i]) + bits2f((u32)(u16)v1[i]))
                        + (bits2f((u32)(u16)v2[i]) + bits2f((u32)(u16)v3[i]));
            }
        }
        for (; j < end; ++j) {
            bfx8 v = *(const bfx8*)(fb + (size_t)csr[j] * D_DIM + lane * 8);
#pragma unroll
            for (int i = 0; i < 8; i++) acc[i] += bits2f((u32)(u16)v[i]);
        }
    } else {
        for (int j = beg; j < end; j++) {
            const float* fp = ff + (size_t)csr[j] * D_DIM + lane * 8;
            f32x4 v0 = *(const f32x4*)fp;
            f32x4 v1 = *(const f32x4*)(fp + 4);
            acc[0] += v0[0]; acc[1] += v0[1]; acc[2] += v0[2]; acc[3] += v0[3];
            acc[4] += v1[0]; acc[5] += v1[1]; acc[6] += v1[2]; acc[7] += v1[3];
        }
    }
    float rc = 1.0f / (float)(c > 1 ? c : 1);
    u16 o[8];
#pragma unroll
    for (int i = 0; i < 8; i++) o[i] = f2b_bits(acc[i] * rc);
    *(bfx8*)(ap + lane * 8) = *(bfx8*)o;
}

// ---------------- fused-grid 128x128 MFMA GEMM, PER-REGION XCD swizzle ----------------
// r12-verified best GEMM config: balanced per-region bijective swizzle (FETCH
// 91MB) + 32KB LDS (5 blocks/CU TLP) + 2-pass coalesced LDS epilogue. FROZEN.
__global__ __launch_bounds__(256) void gemmf_k(
    const u16* __restrict__ A1, const u16* __restrict__ Bt1, float* __restrict__ out1,
    const float* __restrict__ bias0, const int* __restrict__ cnt0,
    const float* __restrict__ bias1, const int* __restrict__ cnt1,
    int M1, int nwg1,
    const u16* __restrict__ A2, const u16* __restrict__ Bt2, float* __restrict__ out2,
    const float* __restrict__ bias2, const int* __restrict__ cnt2, int M2) {
    constexpr int BK = 64;
    __shared__ __align__(16) float SMEM[8192];  // 32 KB
    u16* As = (u16*)SMEM;             // 128*64 u16 = 16 KB
    u16* Bs = (u16*)(SMEM + 4096);    // 16 KB
    float* Cst = SMEM;                // 64x128 f32 = 32 KB (epilogue)

    int tid = threadIdx.x;
    int wid = tid >> 6, lane = tid & 63;

    int orig = blockIdx.x;
    const u16 *A, *Bt;
    float* out;
    const float *b0, *b1;
    const int *c0, *c1;
    int M, KT, local;
    if (orig < nwg1) {
        int nw = nwg1;
        int q8 = nw >> 3, r8 = nw & 7, xc = orig & 7;
        local = (xc < r8 ? xc * (q8 + 1) : r8 * (q8 + 1) + (xc - r8) * q8) + (orig >> 3);
        A = A1; Bt = Bt1; out = out1; b0 = bias0; c0 = cnt0; b1 = bias1; c1 = cnt1;
        M = M1; KT = 1024;
    } else {
        int o2 = orig - nwg1;
        int nw = gridDim.x - nwg1;
        int q8 = nw >> 3, r8 = nw & 7, xc = o2 & 7;
        local = (xc < r8 ? xc * (q8 + 1) : r8 * (q8 + 1) + (xc - r8) * q8) + (o2 >> 3);
        A = A2; Bt = Bt2; out = out2; b0 = bias2; c0 = cnt2; b1 = nullptr; c1 = nullptr;
        M = M2; KT = 512;
    }
    int tileN = (local & 3) * 128;   // N-major: panel's 4 N-tiles adjacent in local
    int tileM = (local >> 2) * 128;

    int wm = wid >> 1, wn = wid & 1;
    int m0 = wm * 64, n0 = wn * 64;

    int l8 = lane >> 3;
    int cc = (lane & 7) ^ l8;  // pre-swizzled source chunk
    int lq = lane >> 4, lr = lane & 15;

    f32x4 acc[4][4] = {};

    for (int k0 = 0; k0 < KT; k0 += BK) {
#pragma unroll
        for (int i = 0; i < 4; i++) {
            int jj = wid * 4 + i;
            int row = tileM + jj * 8 + l8;
            if (row > M - 1) row = M - 1;
            const u16* srcA = A + (size_t)row * KT + k0 + cc * 8;
            __builtin_amdgcn_global_load_lds(
                (const __attribute__((address_space(1))) void*)srcA,
                (__attribute__((address_space(3))) void*)&As[jj * 8 * BK],
                16, 0, 0);
            int nrow = tileN + jj * 8 + l8;
            const u16* srcB = Bt + (size_t)nrow * KT + k0 + cc * 8;
            __builtin_amdgcn_global_load_lds(
                (const __attribute__((address_space(1))) void*)srcB,
                (__attribute__((address_space(3))) void*)&Bs[jj * 8 * BK],
                16, 0, 0);
        }
        __syncthreads();

#pragma unroll
        for (int kk = 0; kk < 2; kk++) {
            bfx8 a[4], b[4];
#pragma unroll
            for (int m = 0; m < 4; m++) {
                int rw = m0 + m * 16 + lr;
                int cp = ((kk << 2) | lq) ^ (rw & 7);
                a[m] = *(const bfx8*)&As[rw * BK + cp * 8];
            }
#pragma unroll
            for (int n = 0; n < 4; n++) {
                int rw = n0 + n * 16 + lr;
                int cp = ((kk << 2) | lq) ^ (rw & 7);
                b[n] = *(const bfx8*)&Bs[rw * BK + cp * 8];
            }
#pragma unroll
            for (int m = 0; m < 4; m++)
#pragma unroll
                for (int n = 0; n < 4; n++)
                    acc[m][n] = __builtin_amdgcn_mfma_f32_16x16x32_bf16(
                        a[m], b[n], acc[m][n], 0, 0, 0);
        }
        __syncthreads();
    }

    // ---- epilogue: two 64-row passes through 32 KB LDS ----
#pragma unroll
    for (int h = 0; h < 2; ++h) {
        if (wm == h) {
#pragma unroll
            for (int m = 0; m < 4; m++)
#pragma unroll
                for (int r2 = 0; r2 < 4; r2++) {
                    int row_l = m * 16 + lq * 4 + r2;  // 0..63 within half
#pragma unroll
                    for (int n = 0; n < 4; n++) {
                        int col_l = n0 + n * 16 + lr;
                        Cst[row_l * 128 + col_l] = acc[m][n][r2];
                    }
                }
        }
        __syncthreads();
#pragma unroll
        for (int it = 0; it < 8; it++) {
            int idx2 = it * 256 + tid;
            int row_l = idx2 >> 5, q = idx2 & 31;
            int grow = tileM + h * 64 + row_l;
            if (grow < M) {
                f32x4 v = *(const f32x4*)&Cst[row_l * 128 + q * 4];
                int gcol = tileN + q * 4;
                if (c0 && c0[grow] > 0) { f32x4 bv = *(const f32x4*)&b0[gcol]; v = v + bv; }
                if (c1 && c1[grow] > 0) { f32x4 bv = *(const f32x4*)&b1[gcol]; v = v + bv; }
                *(f32x4*)&out[(size_t)grow * D_DIM + gcol] = v;
            }
        }
        __syncthreads();  // Cst reused by next half
    }
}

extern "C" void kernel_launch(void* const* d_in, const int* in_sizes, int n_in,
                              void* d_out, int out_size, void* d_ws, size_t ws_size,
                              hipStream_t stream) {
    const float* featA = (const float*)d_in[0];
    const float* featB = (const float*)d_in[1];
    const float* Waa = (const float*)d_in[2];
    const float* baa = (const float*)d_in[3];
    const float* Wab = (const float*)d_in[4];
    const float* bab = (const float*)d_in[5];
    const float* Wba = (const float*)d_in[6];
    const float* bba = (const float*)d_in[7];
    const int* src_aa = (const int*)d_in[8];
    const int* dst_aa = (const int*)d_in[9];
    const int* src_ab = (const int*)d_in[10];
    const int* dst_ab = (const int*)d_in[11];
    const int* src_ba = (const int*)d_in[12];
    const int* dst_ba = (const int*)d_in[13];

    int NA = in_sizes[0] / D_DIM, NB = in_sizes[1] / D_DIM;
    int Eaa = in_sizes[8], Eab = in_sizes[10], Eba = in_sizes[12];

    float* out = (float*)d_out;
    char* ws = (char*)d_ws;
    size_t off = 0;
    u16* Acat = (u16*)(ws + off); off += (size_t)NA * 1024 * 2;   // [NA][1024]: aa | ba
    u16* Aab  = (u16*)(ws + off); off += (size_t)NB * 512 * 2;    // [NB][512]
    u16* WtC  = (u16*)(ws + off); off += (size_t)512 * 1024 * 2;
    u16* WtAb = (u16*)(ws + off); off += (size_t)512 * 512 * 2;
    int* cnt_aa = (int*)(ws + off); off += (size_t)NA * 4;        // [aa|ba|ab] contiguous
    int* cnt_ba = (int*)(ws + off); off += (size_t)NA * 4;
    int* cnt_ab = (int*)(ws + off); off += (size_t)NB * 4;
    int* cur_aa = (int*)(ws + off); off += (size_t)NA * 4;        // [aa|ba|ab] contiguous
    int* cur_ba = (int*)(ws + off); off += (size_t)NA * 4;
    int* cur_ab = (int*)(ws + off); off += (size_t)NB * 4;
    int* csr_aa = (int*)(ws + off); off += (size_t)Eaa * 4;
    int* csr_ba = (int*)(ws + off); off += (size_t)Eba * 4;
    int* csr_ab = (int*)(ws + off); off += (size_t)Eab * 4;
    int nc0 = (NA + 255) / 256, nc1 = (NA + 255) / 256, nc2 = (NB + 255) / 256;
    int* csum = (int*)(ws + off); off += (size_t)(nc0 + nc1 + nc2) * 4;

    // optional bf16 feature copies (budget-checked)
    size_t cA = (size_t)NA * 512 * 2, cB = (size_t)NB * 512 * 2;
    u16* fAbf = nullptr;
    u16* fBbf = nullptr;
    if (off + cA + cB <= ws_size) {
        fAbf = (u16*)(ws + off); off += cA;
        fBbf = (u16*)(ws + off); off += cB;
    }

    // zero counts only (aggregates fully overwritten by pull)
    hipMemsetAsync(cnt_aa, 0, (size_t)(2 * NA + NB) * 4, stream);

    int Etot = Eaa + Eba + Eab;

    // weight transpose + degree count (fast; conv moved to fill stage)
    int nbPrep = (512 * 1024 + 512 * 512) / 256;  // 3072
    int nbCount = (Etot + 255) / 256;
    prepcnt_k<<<nbPrep + nbCount, 256, 0, stream>>>(
        Waa, Wba, Wab, WtC, WtAb, nbPrep,
        dst_aa, cnt_aa, Eaa, dst_ba, cnt_ba, Eba, dst_ab, cnt_ab, Eab);

    int ncTot = nc0 + nc1 + nc2;
    chunksum_k<<<ncTot, 256, 0, stream>>>(cnt_aa, csum, NA, NA, NB, nc0, nc1, nc2);
    chunkscan_k<<<1, 256, 0, stream>>>(csum, nc0, nc1, nc2);
    scanfinal_k<<<ncTot, 256, 0, stream>>>(cnt_aa, csum, cur_aa, NA, NA, NB, nc0, nc1, nc2);

    // CSR fill (atomic, ~20us) overlapped with feature bf16 conversion (~60us)
    int nbFill = (Etot + 255) / 256;
    int nbConv = fAbf ? 2048 : 0;
    fillconv_k<<<nbFill + nbConv, 256, 0, stream>>>(
        src_aa, dst_aa, cur_aa, csr_aa, Eaa,
        src_ba, dst_ba, cur_ba, csr_ba, Eba,
        src_ab, dst_ab, cur_ab, csr_ab, Eab,
        nbFill,
        featA, featB, fAbf, fBbf, NA * 64, (NA + NB) * 64, nbConv);

    int nPull = 2 * NA + NB;
    pull3_k<<<(nPull + 3) / 4, 256, 0, stream>>>(
        fAbf, fBbf, featA, featB, fAbf != nullptr,
        cur_aa, cnt_aa, csr_aa, csr_ba, csr_ab, Acat, Aab, NA, NB);

    int nwg1 = ((NA + 127) / 128) * 4;
    int nwg2 = ((NB + 127) / 128) * 4;
    gemmf_k<<<nwg1 + nwg2, 256, 0, stream>>>(
        Acat, WtC, out, baa, cnt_aa, bba, cnt_ba, NA, nwg1,
        Aab, WtAb, out + (size_t)NA * D_DIM, bab, cnt_ab, NB);
}

// Round 15
// 364.555 us; speedup vs baseline: 1.0301x; 1.0301x over previous
//
#include <hip/hip_runtime.h>

typedef unsigned short u16;
typedef unsigned int u32;
typedef float f32x4 __attribute__((ext_vector_type(4)));
typedef short bfx8 __attribute__((ext_vector_type(8)));

#define D_DIM 512

__device__ __forceinline__ float bits2f(u32 b) {
    return __uint_as_float(b << 16);
}
__device__ __forceinline__ u16 f2b_bits(float f) {
    u32 u = __float_as_uint(f);
    u32 r = (u + 0x7fffu + ((u >> 16) & 1u)) >> 16;  // RNE
    return (u16)r;
}

// ---------------- fused prep: weight transpose + feat conv + degree count ----------
// r13-verified best arrangement (r14's fill/conv split regressed).
__global__ __launch_bounds__(256) void prep_all_k(
    const float* __restrict__ Waa, const float* __restrict__ Wba,
    const float* __restrict__ Wab,
    u16* __restrict__ WtC, u16* __restrict__ WtAb,
    const float* __restrict__ fa, const float* __restrict__ fb,
    u16* __restrict__ oa, u16* __restrict__ ob, int nA8, int nTot8,
    int nbPrep, int nbConv,
    const int* __restrict__ d0, int* __restrict__ c0, int E0,
    const int* __restrict__ d1, int* __restrict__ c1, int E1,
    const int* __restrict__ d2, int* __restrict__ c2, int E2) {
    int g = blockIdx.x, tid = threadIdx.x;
    if (g < nbPrep) {
        int idx = g * 256 + tid;
        if (idx < 512 * 1024) {
            int n = idx >> 10, k = idx & 1023;
            float v = (k < 512) ? Waa[k * 512 + n] : Wba[(k - 512) * 512 + n];
            WtC[idx] = f2b_bits(v);
        } else {
            int idx2 = idx - 512 * 1024;
            int n = idx2 >> 9, k = idx2 & 511;
            WtAb[idx2] = f2b_bits(Wab[k * 512 + n]);
        }
    } else if (g < nbPrep + nbConv) {
        for (int i = (g - nbPrep) * 256 + tid; i < nTot8; i += nbConv * 256) {
            const float* src; u16* dst; int j;
            if (i < nA8) { src = fa; dst = oa; j = i; }
            else { src = fb; dst = ob; j = i - nA8; }
            f32x4 a = *(const f32x4*)(src + (size_t)j * 8);
            f32x4 b = *(const f32x4*)(src + (size_t)j * 8 + 4);
            u16 o[8];
            o[0] = f2b_bits(a[0]); o[1] = f2b_bits(a[1]); o[2] = f2b_bits(a[2]); o[3] = f2b_bits(a[3]);
            o[4] = f2b_bits(b[0]); o[5] = f2b_bits(b[1]); o[6] = f2b_bits(b[2]); o[7] = f2b_bits(b[3]);
            *(bfx8*)(dst + (size_t)j * 8) = *(bfx8*)o;
        }
    } else {
        int i = (g - nbPrep - nbConv) * 256 + tid;
        if (i < E0) atomicAdd(&c0[d0[i]], 1);
        else if (i < E0 + E1) atomicAdd(&c1[d1[i - E0]], 1);
        else if (i < E0 + E1 + E2) atomicAdd(&c2[d2[i - E0 - E1]], 1);
    }
}

// ---------------- parallel scan: chunk sums (CH=256) ----------------
__global__ __launch_bounds__(256) void chunksum_k(
    const int* __restrict__ cnt, int* __restrict__ csum,
    int n0, int n1, int n2, int nc0, int nc1, int nc2) {
    __shared__ int ws4[4];
    int g = blockIdx.x;
    int lc, base, n, cbase;
    if (g < nc0) { lc = g; base = 0; n = n0; cbase = 0; }
    else if (g < nc0 + nc1) { lc = g - nc0; base = n0; n = n1; cbase = nc0; }
    else { lc = g - nc0 - nc1; base = n0 + n1; n = n2; cbase = nc0 + nc1; }
    int tid = threadIdx.x, lane = tid & 63, wv = tid >> 6;
    int i = lc * 256 + tid;
    int v = (i < n) ? cnt[base + i] : 0;
#pragma unroll
    for (int d = 32; d; d >>= 1) v += __shfl_down(v, d, 64);
    if (lane == 0) ws4[wv] = v;
    __syncthreads();
    if (tid == 0) csum[cbase + lc] = ws4[0] + ws4[1] + ws4[2] + ws4[3];
}

// ---------------- parallel scan: exclusive scan of chunk sums (1 block) ----------------
__global__ __launch_bounds__(256) void chunkscan_k(int* __restrict__ csum,
                                                   int nc0, int nc1, int nc2) {
    __shared__ int ws4[4];
    int tid = threadIdx.x, lane = tid & 63, wv = tid >> 6;
    int ncs[3] = {nc0, nc1, nc2};
    int cb = 0;
    for (int e = 0; e < 3; e++) {
        int nc = ncs[e];  // requires nc <= 256 (N <= 65536)
        int v = (tid < nc) ? csum[cb + tid] : 0;
        int x = v;
#pragma unroll
        for (int d = 1; d < 64; d <<= 1) {
            int t = __shfl_up(x, d, 64);
            if (lane >= d) x += t;
        }
        if (lane == 63) ws4[wv] = x;
        __syncthreads();
        int woff = 0;
        for (int w = 0; w < wv; w++) woff += ws4[w];
        if (tid < nc) csum[cb + tid] = woff + x - v;  // exclusive
        __syncthreads();
        cb += nc;
    }
}

// ---------------- parallel scan: final per-element exclusive offsets ----------------
__global__ __launch_bounds__(256) void scanfinal_k(
    const int* __restrict__ cnt, const int* __restrict__ csum, int* __restrict__ cur,
    int n0, int n1, int n2, int nc0, int nc1, int nc2) {
    __shared__ int ws4[4];
    int g = blockIdx.x;
    int lc, base, n, cbase;
    if (g < nc0) { lc = g; base = 0; n = n0; cbase = 0; }
    else if (g < nc0 + nc1) { lc = g - nc0; base = n0; n = n1; cbase = nc0; }
    else { lc = g - nc0 - nc1; base = n0 + n1; n = n2; cbase = nc0 + nc1; }
    int tid = threadIdx.x, lane = tid & 63, wv = tid >> 6;
    int i = lc * 256 + tid;
    int v = (i < n) ? cnt[base + i] : 0;
    int x = v;
#pragma unroll
    for (int d = 1; d < 64; d <<= 1) {
        int t = __shfl_up(x, d, 64);
        if (lane >= d) x += t;
    }
    if (lane == 63) ws4[wv] = x;
    __syncthreads();
    int woff = 0;
    for (int w = 0; w < wv; w++) woff += ws4[w];
    if (i < n) cur[base + i] = csum[cbase + lc] + woff + x - v;
}

// ---------------- CSR bucket fill (3 etypes fused) ----------------
__global__ void fill3_k(const int* __restrict__ s0, const int* __restrict__ d0,
                        int* __restrict__ u0, int* __restrict__ r0, int E0,
                        const int* __restrict__ s1, const int* __restrict__ d1,
                        int* __restrict__ u1, int* __restrict__ r1, int E1,
                        const int* __restrict__ s2, const int* __restrict__ d2,
                        int* __restrict__ u2, int* __restrict__ r2, int E2) {
    int i = blockIdx.x * 256 + threadIdx.x;
    if (i < E0) { int slot = atomicAdd(&u0[d0[i]], 1); r0[slot] = s0[i]; }
    else if (i < E0 + E1) { int j = i - E0; int slot = atomicAdd(&u1[d1[j]], 1); r1[slot] = s1[j]; }
    else if (i < E0 + E1 + E2) { int j = i - E0 - E1; int slot = atomicAdd(&u2[d2[j]], 1); r2[slot] = s2[j]; }
}

// ---------------- fused pull-mean (wave per (etype,node)), 4-way MLP ----------------
__global__ __launch_bounds__(256) void pull3_k(
    const u16* __restrict__ fAb, const u16* __restrict__ fBb,
    const float* __restrict__ fAf, const float* __restrict__ fBf, int usebf,
    const int* __restrict__ curb, const int* __restrict__ cntb,
    const int* __restrict__ csr0, const int* __restrict__ csr1,
    const int* __restrict__ csr2,
    u16* __restrict__ Acat, u16* __restrict__ Aab, int NA, int NB) {
    int wid = threadIdx.x >> 6, lane = threadIdx.x & 63;
    int t = blockIdx.x * 4 + wid;
    if (t >= 2 * NA + NB) return;
    const u16* fb; const float* ff; const int* csr; u16* ap;
    if (t < NA) { fb = fAb; ff = fAf; csr = csr0; ap = Acat + (size_t)t * 1024; }
    else if (t < 2 * NA) { fb = fBb; ff = fBf; csr = csr1; ap = Acat + (size_t)(t - NA) * 1024 + 512; }
    else { fb = fAb; ff = fAf; csr = csr2; ap = Aab + (size_t)(t - 2 * NA) * 512; }
    int end = curb[t], c = cntb[t], beg = end - c;
    float acc[8] = {};
    if (usebf) {
        int j = beg;
        for (; j + 4 <= end; j += 4) {
            int s0 = csr[j], s1 = csr[j + 1], s2 = csr[j + 2], s3 = csr[j + 3];
            bfx8 v0 = *(const bfx8*)(fb + (size_t)s0 * D_DIM + lane * 8);
            bfx8 v1 = *(const bfx8*)(fb + (size_t)s1 * D_DIM + lane * 8);
            bfx8 v2 = *(const bfx8*)(fb + (size_t)s2 * D_DIM + lane * 8);
            bfx8 v3 = *(const bfx8*)(fb + (size_t)s3 * D_DIM + lane * 8);
#pragma unroll
            for (int i = 0; i < 8; i++) {
                acc[i] += (bits2f((u32)(u16)v0[i]) + bits2f((u32)(u16)v1[i]))
                        + (bits2f((u32)(u16)v2[i]) + bits2f((u32)(u16)v3[i]));
            }
        }
        for (; j < end; ++j) {
            bfx8 v = *(const bfx8*)(fb + (size_t)csr[j] * D_DIM + lane * 8);
#pragma unroll
            for (int i = 0; i < 8; i++) acc[i] += bits2f((u32)(u16)v[i]);
        }
    } else {
        for (int j = beg; j < end; j++) {
            const float* fp = ff + (size_t)csr[j] * D_DIM + lane * 8;
            f32x4 v0 = *(const f32x4*)fp;
            f32x4 v1 = *(const f32x4*)(fp + 4);
            acc[0] += v0[0]; acc[1] += v0[1]; acc[2] += v0[2]; acc[3] += v0[3];
            acc[4] += v1[0]; acc[5] += v1[1]; acc[6] += v1[2]; acc[7] += v1[3];
        }
    }
    float rc = 1.0f / (float)(c > 1 ? c : 1);
    u16 o[8];
#pragma unroll
    for (int i = 0; i < 8; i++) o[i] = f2b_bits(acc[i] * rc);
    *(bfx8*)(ap + lane * 8) = *(bfx8*)o;
}

// ---------------- fused-grid 128x128 MFMA GEMM, PER-REGION XCD swizzle ----------------
// r12-verified best GEMM config, FROZEN K-loop. NEW (r15): epilogue C-tile
// chunk swizzle c' = c ^ (((row>>2)&3)<<2) — write conflicts 4-way -> 2-way
// (free, m136), read stays conflict-free (per-row bijective permutation).
// Source of the 1.6M SQ_LDS_BANK_CONFLICT (K-loop measured 0 in r3/r4).
__global__ __launch_bounds__(256) void gemmf_k(
    const u16* __restrict__ A1, const u16* __restrict__ Bt1, float* __restrict__ out1,
    const float* __restrict__ bias0, const int* __restrict__ cnt0,
    const float* __restrict__ bias1, const int* __restrict__ cnt1,
    int M1, int nwg1,
    const u16* __restrict__ A2, const u16* __restrict__ Bt2, float* __restrict__ out2,
    const float* __restrict__ bias2, const int* __restrict__ cnt2, int M2) {
    constexpr int BK = 64;
    __shared__ __align__(16) float SMEM[8192];  // 32 KB
    u16* As = (u16*)SMEM;             // 128*64 u16 = 16 KB
    u16* Bs = (u16*)(SMEM + 4096);    // 16 KB
    float* Cst = SMEM;                // 64x128 f32 = 32 KB (epilogue)

    int tid = threadIdx.x;
    int wid = tid >> 6, lane = tid & 63;

    int orig = blockIdx.x;
    const u16 *A, *Bt;
    float* out;
    const float *b0, *b1;
    const int *c0, *c1;
    int M, KT, local;
    if (orig < nwg1) {
        int nw = nwg1;
        int q8 = nw >> 3, r8 = nw & 7, xc = orig & 7;
        local = (xc < r8 ? xc * (q8 + 1) : r8 * (q8 + 1) + (xc - r8) * q8) + (orig >> 3);
        A = A1; Bt = Bt1; out = out1; b0 = bias0; c0 = cnt0; b1 = bias1; c1 = cnt1;
        M = M1; KT = 1024;
    } else {
        int o2 = orig - nwg1;
        int nw = gridDim.x - nwg1;
        int q8 = nw >> 3, r8 = nw & 7, xc = o2 & 7;
        local = (xc < r8 ? xc * (q8 + 1) : r8 * (q8 + 1) + (xc - r8) * q8) + (o2 >> 3);
        A = A2; Bt = Bt2; out = out2; b0 = bias2; c0 = cnt2; b1 = nullptr; c1 = nullptr;
        M = M2; KT = 512;
    }
    int tileN = (local & 3) * 128;   // N-major: panel's 4 N-tiles adjacent in local
    int tileM = (local >> 2) * 128;

    int wm = wid >> 1, wn = wid & 1;
    int m0 = wm * 64, n0 = wn * 64;

    int l8 = lane >> 3;
    int cc = (lane & 7) ^ l8;  // pre-swizzled source chunk
    int lq = lane >> 4, lr = lane & 15;

    f32x4 acc[4][4] = {};

    for (int k0 = 0; k0 < KT; k0 += BK) {
#pragma unroll
        for (int i = 0; i < 4; i++) {
            int jj = wid * 4 + i;
            int row = tileM + jj * 8 + l8;
            if (row > M - 1) row = M - 1;
            const u16* srcA = A + (size_t)row * KT + k0 + cc * 8;
            __builtin_amdgcn_global_load_lds(
                (const __attribute__((address_space(1))) void*)srcA,
                (__attribute__((address_space(3))) void*)&As[jj * 8 * BK],
                16, 0, 0);
            int nrow = tileN + jj * 8 + l8;
            const u16* srcB = Bt + (size_t)nrow * KT + k0 + cc * 8;
            __builtin_amdgcn_global_load_lds(
                (const __attribute__((address_space(1))) void*)srcB,
                (__attribute__((address_space(3))) void*)&Bs[jj * 8 * BK],
                16, 0, 0);
        }
        __syncthreads();

#pragma unroll
        for (int kk = 0; kk < 2; kk++) {
            bfx8 a[4], b[4];
#pragma unroll
            for (int m = 0; m < 4; m++) {
                int rw = m0 + m * 16 + lr;
                int cp = ((kk << 2) | lq) ^ (rw & 7);
                a[m] = *(const bfx8*)&As[rw * BK + cp * 8];
            }
#pragma unroll
            for (int n = 0; n < 4; n++) {
                int rw = n0 + n * 16 + lr;
                int cp = ((kk << 2) | lq) ^ (rw & 7);
                b[n] = *(const bfx8*)&Bs[rw * BK + cp * 8];
            }
#pragma unroll
            for (int m = 0; m < 4; m++)
#pragma unroll
                for (int n = 0; n < 4; n++)
                    acc[m][n] = __builtin_amdgcn_mfma_f32_16x16x32_bf16(
                        a[m], b[n], acc[m][n], 0, 0, 0);
        }
        __syncthreads();
    }

    // ---- epilogue: two 64-row passes through 32 KB LDS, chunk-swizzled ----
#pragma unroll
    for (int h = 0; h < 2; ++h) {
        if (wm == h) {
#pragma unroll
            for (int m = 0; m < 4; m++)
#pragma unroll
                for (int r2 = 0; r2 < 4; r2++) {
                    int row_l = m * 16 + lq * 4 + r2;  // 0..63 within half
                    int swz = ((row_l >> 2) & 3) << 2;
#pragma unroll
                    for (int n = 0; n < 4; n++) {
                        int col_l = n0 + n * 16 + lr;
                        int cph = ((col_l >> 2) ^ swz) * 4 + (col_l & 3);
                        Cst[row_l * 128 + cph] = acc[m][n][r2];
                    }
                }
        }
        __syncthreads();
#pragma unroll
        for (int it = 0; it < 8; it++) {
            int idx2 = it * 256 + tid;
            int row_l = idx2 >> 5, q = idx2 & 31;
            int grow = tileM + h * 64 + row_l;
            if (grow < M) {
                int qph = q ^ (((row_l >> 2) & 3) << 2);
                f32x4 v = *(const f32x4*)&Cst[row_l * 128 + qph * 4];
                int gcol = tileN + q * 4;
                if (c0 && c0[grow] > 0) { f32x4 bv = *(const f32x4*)&b0[gcol]; v = v + bv; }
                if (c1 && c1[grow] > 0) { f32x4 bv = *(const f32x4*)&b1[gcol]; v = v + bv; }
                *(f32x4*)&out[(size_t)grow * D_DIM + gcol] = v;
            }
        }
        __syncthreads();  // Cst reused by next half
    }
}

extern "C" void kernel_launch(void* const* d_in, const int* in_sizes, int n_in,
                              void* d_out, int out_size, void* d_ws, size_t ws_size,
                              hipStream_t stream) {
    const float* featA = (const float*)d_in[0];
    const float* featB = (const float*)d_in[1];
    const float* Waa = (const float*)d_in[2];
    const float* baa = (const float*)d_in[3];
    const float* Wab = (const float*)d_in[4];
    const float* bab = (const float*)d_in[5];
    const float* Wba = (const float*)d_in[6];
    const float* bba = (const float*)d_in[7];
    const int* src_aa = (const int*)d_in[8];
    const int* dst_aa = (const int*)d_in[9];
    const int* src_ab = (const int*)d_in[10];
    const int* dst_ab = (const int*)d_in[11];
    const int* src_ba = (const int*)d_in[12];
    const int* dst_ba = (const int*)d_in[13];

    int NA = in_sizes[0] / D_DIM, NB = in_sizes[1] / D_DIM;
    int Eaa = in_sizes[8], Eab = in_sizes[10], Eba = in_sizes[12];

    float* out = (float*)d_out;
    char* ws = (char*)d_ws;
    size_t off = 0;
    u16* Acat = (u16*)(ws + off); off += (size_t)NA * 1024 * 2;   // [NA][1024]: aa | ba
    u16* Aab  = (u16*)(ws + off); off += (size_t)NB * 512 * 2;    // [NB][512]
    u16* WtC  = (u16*)(ws + off); off += (size_t)512 * 1024 * 2;
    u16* WtAb = (u16*)(ws + off); off += (size_t)512 * 512 * 2;
    int* cnt_aa = (int*)(ws + off); off += (size_t)NA * 4;        // [aa|ba|ab] contiguous
    int* cnt_ba = (int*)(ws + off); off += (size_t)NA * 4;
    int* cnt_ab = (int*)(ws + off); off += (size_t)NB * 4;
    int* cur_aa = (int*)(ws + off); off += (size_t)NA * 4;        // [aa|ba|ab] contiguous
    int* cur_ba = (int*)(ws + off); off += (size_t)NA * 4;
    int* cur_ab = (int*)(ws + off); off += (size_t)NB * 4;
    int* csr_aa = (int*)(ws + off); off += (size_t)Eaa * 4;
    int* csr_ba = (int*)(ws + off); off += (size_t)Eba * 4;
    int* csr_ab = (int*)(ws + off); off += (size_t)Eab * 4;
    int nc0 = (NA + 255) / 256, nc1 = (NA + 255) / 256, nc2 = (NB + 255) / 256;
    int* csum = (int*)(ws + off); off += (size_t)(nc0 + nc1 + nc2) * 4;

    // optional bf16 feature copies (budget-checked)
    size_t cA = (size_t)NA * 512 * 2, cB = (size_t)NB * 512 * 2;
    u16* fAbf = nullptr;
    u16* fBbf = nullptr;
    if (off + cA + cB <= ws_size) {
        fAbf = (u16*)(ws + off); off += cA;
        fBbf = (u16*)(ws + off); off += cB;
    }

    // zero counts only (aggregates fully overwritten by pull)
    hipMemsetAsync(cnt_aa, 0, (size_t)(2 * NA + NB) * 4, stream);

    int Etot = Eaa + Eba + Eab;

    // fused prep: weight transpose + feature conversion + degree count (r13 best)
    int nbPrep = (512 * 1024 + 512 * 512) / 256;  // 3072
    int nbConv = fAbf ? 2048 : 0;
    int nbCount = (Etot + 255) / 256;
    prep_all_k<<<nbPrep + nbConv + nbCount, 256, 0, stream>>>(
        Waa, Wba, Wab, WtC, WtAb,
        featA, featB, fAbf, fBbf, NA * 64, (NA + NB) * 64,
        nbPrep, nbConv,
        dst_aa, cnt_aa, Eaa, dst_ba, cnt_ba, Eba, dst_ab, cnt_ab, Eab);

    int ncTot = nc0 + nc1 + nc2;
    chunksum_k<<<ncTot, 256, 0, stream>>>(cnt_aa, csum, NA, NA, NB, nc0, nc1, nc2);
    chunkscan_k<<<1, 256, 0, stream>>>(csum, nc0, nc1, nc2);
    scanfinal_k<<<ncTot, 256, 0, stream>>>(cnt_aa, csum, cur_aa, NA, NA, NB, nc0, nc1, nc2);

    fill3_k<<<(Etot + 255) / 256, 256, 0, stream>>>(
        src_aa, dst_aa, cur_aa, csr_aa, Eaa,
        src_ba, dst_ba, cur_ba, csr_ba, Eba,
        src_ab, dst_ab, cur_ab, csr_ab, Eab);

    int nPull = 2 * NA + NB;
    pull3_k<<<(nPull + 3) / 4, 256, 0, stream>>>(
        fAbf, fBbf, featA, featB, fAbf != nullptr,
        cur_aa, cnt_aa, csr_aa, csr_ba, csr_ab, Acat, Aab, NA, NB);

    int nwg1 = ((NA + 127) / 128) * 4;
    int nwg2 = ((NB + 127) / 128) * 4;
    gemmf_k<<<nwg1 + nwg2, 256, 0, stream>>>(
        Acat, WtC, out, baa, cnt_aa, bba, cnt_ba, NA, nwg1,
        Aab, WtAb, out + (size_t)NA * D_DIM, bab, cnt_ab, NB);
}